// Round 1
// baseline (1488.740 us; speedup 1.0000x reference)
//
#include <hip/hip_runtime.h>
#include <hip/hip_bf16.h>

// ---------------------------------------------------------------------------
// LatentActionGen: x = relu(s0@W0 + s1@W1 + b0 + b1); flat = x@Wf + bf;
// VQ argmin over 30 codes; z = codebook[idx]; loss = 0.5*||q-f||^2; perplexity.
//
// Design: memory-bound (1.07 GB of s0/s1 @ 6.3 TB/s => 170 us floor).
// GEMM in split-bf16 (hi+lo, 3 MFMA terms) for fp32-level accuracy.
// No LDS, no barriers: B (weights) pre-packed in MFMA fragment order so waves
// stream it with coalesced 1KB loads from L2; A loaded direct-to-register and
// converted in-flight. 2-deep software pipeline with static double buffers.
// ---------------------------------------------------------------------------

typedef __bf16 bf16x8 __attribute__((ext_vector_type(8)));
typedef float  floatx4 __attribute__((ext_vector_type(4)));

#define NROWS  32768
#define DIM    4096
#define HID    128
#define NCODE  30
#define NCHUNK 256   // 8192 total k (W0 then W1) / 32 per MFMA step

// output layout (flat, reference return order): z[N*4], loss[N], perp[1], idx[N]
#define Z_OFF    0
#define LOSS_OFF (NROWS * 4)            // 131072
#define PERP_OFF (LOSS_OFF + NROWS)     // 163840
#define IDX_OFF  (PERP_OFF + 1)         // 163841

#define BPACK_OFF_B 256                 // ws: [0,120) hist, [256, 256+4MB) bpack

// ---------------------------------------------------------------------------
// Pack W0|W1 as bf16 hi/lo in exact B-fragment order.
// B-frag (mfma_f32_16x16x32_bf16): lane l holds B[k = 8*(l>>4)+j][n = 16t+(l&15)].
// Layout (bf16x8 units): unit[(c*1024) + hilo*512 + t*64 + l]
//   = {W[c*32 + 8q + j][16t + n'] : j=0..7}, c<128 -> W0, else W1.
// Waves in the main kernel then load each (t,hilo) fragment as one contiguous
// 1KB coalesced read.
// ---------------------------------------------------------------------------
__global__ __launch_bounds__(256) void vq_prep_pack(
    const float* __restrict__ W0, const float* __restrict__ W1,
    __bf16* __restrict__ bpack)
{
  int unit = blockIdx.x * 256 + threadIdx.x;   // 0..131071 = c*512 + t*64 + l
  int c  = unit >> 9;
  int t  = (unit >> 6) & 7;
  int l  = unit & 63;
  int q  = l >> 4;
  int np = l & 15;
  int n  = 16 * t + np;
  int kk = (c & 127) * 32 + q * 8;
  const float* W = (c < 128) ? W0 : W1;
  const float* src = W + (size_t)kk * HID + n;

  bf16x8 hi, lo;
#pragma unroll
  for (int j = 0; j < 8; ++j) {
    float x = src[(size_t)j * HID];
    __bf16 h = (__bf16)x;            // RNE
    hi[j] = h;
    lo[j] = (__bf16)(x - (float)h);  // residual, also RNE
  }
  bf16x8* base = (bf16x8*)bpack + (size_t)c * 1024;
  base[t * 64 + l]       = hi;
  base[512 + t * 64 + l] = lo;
}

// ---------------------------------------------------------------------------
// Main fused kernel: 256 blocks x 256 threads. Wave owns 32 rows x 128 cols
// (2 row-tiles x 8 col-tiles of 16x16x32 MFMA). acc = 64 VGPRs/lane.
// ---------------------------------------------------------------------------
struct AStep { floatx4 a[2][2]; };          // [row-tile][k-half]
struct BStep { bf16x8 bh[8]; bf16x8 bl[8]; };

__global__ __launch_bounds__(256, 1) void vq_main(
    const float* __restrict__ s0, const float* __restrict__ s1,
    const float* __restrict__ b0, const float* __restrict__ b1,
    const float* __restrict__ Wf, const float* __restrict__ bf_p,
    const float* __restrict__ cb, const __bf16* __restrict__ bpack,
    float* __restrict__ out, int* __restrict__ hist)
{
  const int tid  = threadIdx.x;
  const int wave = tid >> 6;
  const int lane = tid & 63;
  const int q    = lane >> 4;
  const int np   = lane & 15;
  const int rowbase = blockIdx.x * 128 + wave * 32;

  const size_t arow0 = (size_t)(rowbase + np) * DIM;        // A-frag m = lane&15
  const size_t arow1 = (size_t)(rowbase + 16 + np) * DIM;
  const int koff_lane = q * 8;                               // A-frag k-group

  floatx4 acc[2][8];
#pragma unroll
  for (int rt = 0; rt < 2; ++rt)
#pragma unroll
    for (int t = 0; t < 8; ++t)
      acc[rt][t] = (floatx4){0.f, 0.f, 0.f, 0.f};

  AStep as0, as1;
  BStep bs0, bs1;

  auto issueA = [&](int c, AStep& st) {
    const float* abase = (c < 128) ? s0 : s1;
    size_t koff = (size_t)(c & 127) * 32 + koff_lane;
    const floatx4* p0 = (const floatx4*)(abase + arow0 + koff);
    st.a[0][0] = p0[0]; st.a[0][1] = p0[1];
    const floatx4* p1 = (const floatx4*)(abase + arow1 + koff);
    st.a[1][0] = p1[0]; st.a[1][1] = p1[1];
  };
  auto issueB = [&](int c, BStep& st) {
    const bf16x8* bp = (const bf16x8*)bpack + (size_t)c * 1024 + lane;
#pragma unroll
    for (int t = 0; t < 8; ++t) {
      st.bh[t] = bp[t * 64];
      st.bl[t] = bp[512 + t * 64];
    }
  };
  auto compute = [&](const AStep& as, const BStep& bs) {
    bf16x8 ahi[2], alo[2];
#pragma unroll
    for (int rt = 0; rt < 2; ++rt)
#pragma unroll
      for (int h = 0; h < 2; ++h)
#pragma unroll
        for (int e = 0; e < 4; ++e) {
          float x = as.a[rt][h][e];
          __bf16 hb = (__bf16)x;
          ahi[rt][h * 4 + e] = hb;
          alo[rt][h * 4 + e] = (__bf16)(x - (float)hb);
        }
#pragma unroll
    for (int t = 0; t < 8; ++t)
#pragma unroll
      for (int rt = 0; rt < 2; ++rt) {
        acc[rt][t] = __builtin_amdgcn_mfma_f32_16x16x32_bf16(ahi[rt], bs.bh[t], acc[rt][t], 0, 0, 0);
        acc[rt][t] = __builtin_amdgcn_mfma_f32_16x16x32_bf16(alo[rt], bs.bh[t], acc[rt][t], 0, 0, 0);
        acc[rt][t] = __builtin_amdgcn_mfma_f32_16x16x32_bf16(ahi[rt], bs.bl[t], acc[rt][t], 0, 0, 0);
      }
  };

  // 2-deep pipeline, static buffers (no dynamic buffer index -> stays in regs)
  issueA(0, as0); issueB(0, bs0);
  for (int c = 0; c < NCHUNK; c += 2) {
    issueA(c + 1, as1); issueB(c + 1, bs1);
    compute(as0, bs0);
    int c2 = (c + 2 < NCHUNK) ? (c + 2) : 0;   // last prefetch is dead but harmless
    issueA(c2, as0); issueB(c2, bs0);
    compute(as1, bs1);
  }

  // ---------------- epilogue: bias + relu + flat = x@Wf + bf, VQ ----------
  // C-layout: lane holds x[row = 16rt + 4q + reg][col = 16t + np]
  floatx4 wfv[8];
  float bsum[8];
#pragma unroll
  for (int t = 0; t < 8; ++t) {
    int col = 16 * t + np;
    bsum[t] = b0[col] + b1[col];
    wfv[t] = *(const floatx4*)(Wf + col * 4);
  }
  const floatx4 bfv = *(const floatx4*)bf_p;

#pragma unroll
  for (int rt = 0; rt < 2; ++rt)
#pragma unroll
    for (int rg = 0; rg < 4; ++rg) {
      float p0 = 0.f, p1 = 0.f, p2 = 0.f, p3 = 0.f;
#pragma unroll
      for (int t = 0; t < 8; ++t) {
        float x = acc[rt][t][rg] + bsum[t];
        x = fmaxf(x, 0.f);
        p0 = fmaf(x, wfv[t][0], p0);
        p1 = fmaf(x, wfv[t][1], p1);
        p2 = fmaf(x, wfv[t][2], p2);
        p3 = fmaf(x, wfv[t][3], p3);
      }
      // reduce across the 16 lanes of this quad (cols 0..127)
#pragma unroll
      for (int m = 1; m <= 8; m <<= 1) {
        p0 += __shfl_xor(p0, m, 64);
        p1 += __shfl_xor(p1, m, 64);
        p2 += __shfl_xor(p2, m, 64);
        p3 += __shfl_xor(p3, m, 64);
      }
      if (np == 0) {
        float f0 = p0 + bfv[0], f1 = p1 + bfv[1], f2 = p2 + bfv[2], f3 = p3 + bfv[3];
        int r = rowbase + rt * 16 + q * 4 + rg;
        // reference distance formula: ||f||^2 + ||c||^2 - 2 f.c, first-min-wins
        float fsq = f0 * f0 + f1 * f1 + f2 * f2 + f3 * f3;
        int best = 0;
        float bestd = 3.4e38f;
        floatx4 bc = (floatx4){0.f, 0.f, 0.f, 0.f};
        for (int k = 0; k < NCODE; ++k) {
          floatx4 ck = *(const floatx4*)(cb + k * 4);
          float csq = ck[0] * ck[0] + ck[1] * ck[1] + ck[2] * ck[2] + ck[3] * ck[3];
          float dot = f0 * ck[0] + f1 * ck[1] + f2 * ck[2] + f3 * ck[3];
          float d = fsq + csq - 2.f * dot;
          if (d < bestd) { bestd = d; best = k; bc = ck; }
        }
        *(floatx4*)(out + Z_OFF + (size_t)r * 4) = bc;   // z == quantized
        float d0 = bc[0] - f0, d1 = bc[1] - f1, d2 = bc[2] - f2, d3 = bc[3] - f3;
        out[LOSS_OFF + r] = 0.5f * (d0 * d0 + d1 * d1 + d2 * d2 + d3 * d3);
        out[IDX_OFF + r] = (float)best;
        atomicAdd(&hist[best], 1);
      }
    }
}

// ---------------------------------------------------------------------------
__global__ void vq_perp(const int* __restrict__ hist, float* __restrict__ out)
{
  if (threadIdx.x == 0 && blockIdx.x == 0) {
    float s = 0.f;
    for (int k = 0; k < NCODE; ++k) {
      float p = (float)hist[k] * (1.0f / (float)NROWS);
      s += p * logf(p + 1e-10f);
    }
    out[PERP_OFF] = expf(-s);
  }
}

// ---------------------------------------------------------------------------
extern "C" void kernel_launch(void* const* d_in, const int* in_sizes, int n_in,
                              void* d_out, int out_size, void* d_ws, size_t ws_size,
                              hipStream_t stream)
{
  const float* s0 = (const float*)d_in[0];
  const float* s1 = (const float*)d_in[1];
  const float* W0 = (const float*)d_in[2];
  const float* b0 = (const float*)d_in[3];
  const float* W1 = (const float*)d_in[4];
  const float* b1 = (const float*)d_in[5];
  const float* Wf = (const float*)d_in[6];
  const float* bf = (const float*)d_in[7];
  const float* cb = (const float*)d_in[8];
  float* out = (float*)d_out;
  int* hist = (int*)d_ws;
  __bf16* bpack = (__bf16*)((char*)d_ws + BPACK_OFF_B);

  hipMemsetAsync(d_ws, 0, 256, stream);                       // zero histogram
  vq_prep_pack<<<512, 256, 0, stream>>>(W0, W1, bpack);       // pack B frags
  vq_main<<<256, 256, 0, stream>>>(s0, s1, b0, b1, Wf, bf, cb, bpack, out, hist);
  vq_perp<<<1, 64, 0, stream>>>(hist, out);
}

// Round 2
// 1129.283 us; speedup vs baseline: 1.3183x; 1.3183x over previous
//
#include <hip/hip_runtime.h>
#include <hip/hip_bf16.h>

// ---------------------------------------------------------------------------
// LatentActionGen v2: x = relu(s0@W0 + s1@W1 + b); flat = x@Wf + bf; VQ.
// split-bf16 (3-term) MFMA GEMM. R1 failure: 1 block/CU + defeated register
// pipeline + 4GB B-traffic -> pure latency bound (MfmaUtil 11%).
// v2: 1024 blocks (4/CU, 16 waves/CU), K-split 2 with fp32 partials,
// B staged in LDS via async global_load_lds (shared by 4 waves),
// nontemporal A loads (keep bpack L2-resident), epilogue kernel does
// sum+bias+relu+Wf+VQ with LDS histogram.
// ---------------------------------------------------------------------------

typedef __bf16 bf16x8 __attribute__((ext_vector_type(8)));
typedef float  floatx4 __attribute__((ext_vector_type(4)));

#define NROWS  32768
#define DIM    4096
#define HID    128
#define NCODE  30
#define NCHUNK_TOT 256          // 8192 k / 32
#define NCHUNK_SL  128          // per K-slice (K-split 2)

// output layout: z[N*4], loss[N], perp[1], idx[N]
#define Z_OFF    0
#define LOSS_OFF (NROWS * 4)
#define PERP_OFF (LOSS_OFF + NROWS)
#define IDX_OFF  (PERP_OFF + 1)

// workspace layout
#define HIST_OFF_B   0                      // 256 B
#define BPACK_OFF_B  256                    // 4 MiB packed weights
#define PART_OFF_B   (8u * 1024 * 1024)     // 2 x 16 MiB fp32 partials

#define GLOBAL_AS __attribute__((address_space(1)))
#define LDS_AS    __attribute__((address_space(3)))

__device__ __forceinline__ void async_ld16(const void* g, void* l) {
  // per-lane global addr; LDS dest = wave-uniform base + lane*16
  __builtin_amdgcn_global_load_lds((const GLOBAL_AS void*)g, (LDS_AS void*)l, 16, 0, 0);
}

// ---------------------------------------------------------------------------
// Pack W0|W1 as bf16 hi/lo in B-fragment order (unchanged from v1; verified).
// chunk c (16KB = 8192 bf16): [hi: t*1024B + lane*16][lo: +8192B]
// frag lane l holds B[k=8*(l>>4)+j][n=16t+(l&15)]
// ---------------------------------------------------------------------------
__global__ __launch_bounds__(256) void vq_prep_pack(
    const float* __restrict__ W0, const float* __restrict__ W1,
    __bf16* __restrict__ bpack)
{
  int unit = blockIdx.x * 256 + threadIdx.x;   // c*512 + t*64 + l
  int c  = unit >> 9;
  int t  = (unit >> 6) & 7;
  int l  = unit & 63;
  int q  = l >> 4;
  int np = l & 15;
  int n  = 16 * t + np;
  int kk = (c & 127) * 32 + q * 8;
  const float* W = (c < 128) ? W0 : W1;
  const float* src = W + (size_t)kk * HID + n;

  bf16x8 hi, lo;
#pragma unroll
  for (int j = 0; j < 8; ++j) {
    float x = src[(size_t)j * HID];
    __bf16 h = (__bf16)x;
    hi[j] = h;
    lo[j] = (__bf16)(x - (float)h);
  }
  bf16x8* base = (bf16x8*)bpack + (size_t)c * 1024;
  base[t * 64 + l]       = hi;
  base[512 + t * 64 + l] = lo;
}

// ---------------------------------------------------------------------------
// Main GEMM: 1024 blocks x 256 thr. block = (rowblk, kslice); 64 rows,
// 4096 k. Wave owns 16 rows x 128 cols (acc 32 VGPR). B in LDS (dbuf 2x16KB).
// ---------------------------------------------------------------------------
__global__ __launch_bounds__(256, 4) void vq_main(
    const float* __restrict__ s0, const float* __restrict__ s1,
    const __bf16* __restrict__ bpack, float* __restrict__ partial)
{
  __shared__ __align__(16) char ldsb[2][16384];

  const int tid  = threadIdx.x;
  const int wave = tid >> 6;
  const int lane = tid & 63;
  const int q    = lane >> 4;
  const int np   = lane & 15;
  const int rowblk = blockIdx.x >> 1;
  const int ks     = blockIdx.x & 1;
  const int rowbase = rowblk * 64 + wave * 16;

  const float* A = ks ? s1 : s0;
  const float* arow = A + (size_t)(rowbase + np) * DIM + q * 8;
  const __bf16* bsrc = bpack + (size_t)ks * NCHUNK_SL * 8192;

  floatx4 acc[8];
#pragma unroll
  for (int t = 0; t < 8; ++t) acc[t] = (floatx4){0.f, 0.f, 0.f, 0.f};

  floatx4 a0[2], a1[2];   // two static A buffers (avoid dynamic reg indexing)

  auto loadA0 = [&](int c) {
    const floatx4* p = (const floatx4*)(arow + c * 32);
    a0[0] = __builtin_nontemporal_load(p);
    a0[1] = __builtin_nontemporal_load(p + 1);
  };
  auto loadA1 = [&](int c) {
    const floatx4* p = (const floatx4*)(arow + c * 32);
    a1[0] = __builtin_nontemporal_load(p);
    a1[1] = __builtin_nontemporal_load(p + 1);
  };
  auto stageB = [&](int c, int b) {
    const char* g = (const char*)(bsrc + (size_t)c * 8192);
    char* l = ldsb[b];
#pragma unroll
    for (int i = 0; i < 4; ++i) {
      int off = (i * 4 + wave) * 1024;
      async_ld16(g + off + lane * 16, l + off);
    }
  };
  auto computeF = [&](const floatx4* ar, int b) {
    bf16x8 ahi, alo;
#pragma unroll
    for (int h = 0; h < 2; ++h)
#pragma unroll
      for (int e = 0; e < 4; ++e) {
        float x = ar[h][e];
        __bf16 hb = (__bf16)x;
        ahi[h * 4 + e] = hb;
        alo[h * 4 + e] = (__bf16)(x - (float)hb);
      }
    const bf16x8* lb = (const bf16x8*)ldsb[b];
#pragma unroll
    for (int t = 0; t < 8; ++t) {
      bf16x8 bh = lb[t * 64 + lane];
      bf16x8 bl = lb[512 + t * 64 + lane];
      acc[t] = __builtin_amdgcn_mfma_f32_16x16x32_bf16(ahi, bh, acc[t], 0, 0, 0);
      acc[t] = __builtin_amdgcn_mfma_f32_16x16x32_bf16(alo, bh, acc[t], 0, 0, 0);
      acc[t] = __builtin_amdgcn_mfma_f32_16x16x32_bf16(ahi, bl, acc[t], 0, 0, 0);
    }
  };

  loadA0(0);
  stageB(0, 0);
  for (int c = 0; c < NCHUNK_SL; c += 2) {
    __syncthreads();                       // buf0 staged; buf1 free
    loadA1(c + 1);
    stageB(c + 1, 1);
    computeF(a0, 0);
    __syncthreads();                       // buf1 staged; buf0 free
    if (c + 2 < NCHUNK_SL) {
      loadA0(c + 2);
      stageB(c + 2, 0);
    }
    computeF(a1, 1);
  }

  // store fp32 partial: partial[ks][row][col]
  float* pbase = partial + ((size_t)ks * NROWS) * HID;
#pragma unroll
  for (int r = 0; r < 4; ++r) {
    int row = rowbase + q * 4 + r;
    float* dst = pbase + (size_t)row * HID + np;
#pragma unroll
    for (int t = 0; t < 8; ++t) dst[t * 16] = acc[t][r];
  }
}

// ---------------------------------------------------------------------------
// Epilogue: sum partials + bias + relu + flat = x@Wf + bf, VQ, hist.
// One row per thread. 128 blocks x 256 thr.
// ---------------------------------------------------------------------------
__global__ __launch_bounds__(256) void vq_epi(
    const float* __restrict__ partial,
    const float* __restrict__ b0, const float* __restrict__ b1,
    const float* __restrict__ Wf, const float* __restrict__ bf_p,
    const float* __restrict__ cb,
    float* __restrict__ out, int* __restrict__ hist)
{
  __shared__ float sWf[HID * 4];
  __shared__ float sB[HID];
  __shared__ float sCb[NCODE * 4];
  __shared__ int   sH[NCODE];

  int tid = threadIdx.x;
  for (int i = tid; i < HID * 4; i += 256) sWf[i] = Wf[i];
  for (int i = tid; i < HID; i += 256)     sB[i] = b0[i] + b1[i];
  for (int i = tid; i < NCODE * 4; i += 256) sCb[i] = cb[i];
  if (tid < NCODE) sH[tid] = 0;
  __syncthreads();

  int row = blockIdx.x * 256 + tid;
  const float* p0 = partial + (size_t)row * HID;
  const float* p1 = partial + ((size_t)NROWS + row) * HID;

  float f0 = 0.f, f1 = 0.f, f2 = 0.f, f3 = 0.f;
#pragma unroll 4
  for (int c4 = 0; c4 < HID / 4; ++c4) {
    floatx4 x0 = *(const floatx4*)(p0 + c4 * 4);
    floatx4 x1 = *(const floatx4*)(p1 + c4 * 4);
#pragma unroll
    for (int j = 0; j < 4; ++j) {
      int col = c4 * 4 + j;
      float x = fmaxf(x0[j] + x1[j] + sB[col], 0.f);
      f0 = fmaf(x, sWf[col * 4 + 0], f0);
      f1 = fmaf(x, sWf[col * 4 + 1], f1);
      f2 = fmaf(x, sWf[col * 4 + 2], f2);
      f3 = fmaf(x, sWf[col * 4 + 3], f3);
    }
  }
  f0 += bf_p[0]; f1 += bf_p[1]; f2 += bf_p[2]; f3 += bf_p[3];

  // VQ: reference formula, first-min-wins
  float fsq = f0 * f0 + f1 * f1 + f2 * f2 + f3 * f3;
  int best = 0;
  float bestd = 3.4e38f;
  float bc0 = 0.f, bc1 = 0.f, bc2 = 0.f, bc3 = 0.f;
#pragma unroll
  for (int k = 0; k < NCODE; ++k) {
    float c0 = sCb[k * 4], c1 = sCb[k * 4 + 1], c2 = sCb[k * 4 + 2], c3 = sCb[k * 4 + 3];
    float csq = c0 * c0 + c1 * c1 + c2 * c2 + c3 * c3;
    float dot = f0 * c0 + f1 * c1 + f2 * c2 + f3 * c3;
    float d = fsq + csq - 2.f * dot;
    if (d < bestd) { bestd = d; best = k; bc0 = c0; bc1 = c1; bc2 = c2; bc3 = c3; }
  }
  *(floatx4*)(out + Z_OFF + (size_t)row * 4) = (floatx4){bc0, bc1, bc2, bc3};
  float d0 = bc0 - f0, d1 = bc1 - f1, d2 = bc2 - f2, d3 = bc3 - f3;
  out[LOSS_OFF + row] = 0.5f * (d0 * d0 + d1 * d1 + d2 * d2 + d3 * d3);
  out[IDX_OFF + row] = (float)best;

  atomicAdd(&sH[best], 1);
  __syncthreads();
  if (tid < NCODE) atomicAdd(&hist[tid], sH[tid]);
}

// ---------------------------------------------------------------------------
__global__ void vq_perp(const int* __restrict__ hist, float* __restrict__ out)
{
  if (threadIdx.x == 0 && blockIdx.x == 0) {
    float s = 0.f;
    for (int k = 0; k < NCODE; ++k) {
      float p = (float)hist[k] * (1.0f / (float)NROWS);
      s += p * logf(p + 1e-10f);
    }
    out[PERP_OFF] = expf(-s);
  }
}

// ---------------------------------------------------------------------------
extern "C" void kernel_launch(void* const* d_in, const int* in_sizes, int n_in,
                              void* d_out, int out_size, void* d_ws, size_t ws_size,
                              hipStream_t stream)
{
  const float* s0 = (const float*)d_in[0];
  const float* s1 = (const float*)d_in[1];
  const float* W0 = (const float*)d_in[2];
  const float* b0 = (const float*)d_in[3];
  const float* W1 = (const float*)d_in[4];
  const float* b1 = (const float*)d_in[5];
  const float* Wf = (const float*)d_in[6];
  const float* bf = (const float*)d_in[7];
  const float* cb = (const float*)d_in[8];
  float* out = (float*)d_out;

  int*    hist    = (int*)((char*)d_ws + HIST_OFF_B);
  __bf16* bpack   = (__bf16*)((char*)d_ws + BPACK_OFF_B);
  float*  partial = (float*)((char*)d_ws + PART_OFF_B);

  hipMemsetAsync(d_ws, 0, 256, stream);                         // zero histogram
  vq_prep_pack<<<512, 256, 0, stream>>>(W0, W1, bpack);
  vq_main<<<1024, 256, 0, stream>>>(s0, s1, bpack, partial);
  vq_epi<<<NROWS / 256, 256, 0, stream>>>(partial, b0, b1, Wf, bf, cb, out, hist);
  vq_perp<<<1, 64, 0, stream>>>(hist, out);
}